// Round 1
// baseline (178.476 us; speedup 1.0000x reference)
//
#include <hip/hip_runtime.h>
#include <hip/hip_bf16.h>
#include <stdint.h>

typedef short    bf16x8 __attribute__((ext_vector_type(8)));
typedef float    f32x4  __attribute__((ext_vector_type(4)));
typedef float    f32x16 __attribute__((ext_vector_type(16)));
typedef uint32_t u32x2  __attribute__((ext_vector_type(2)));
typedef uint32_t u32x4  __attribute__((ext_vector_type(4)));
typedef uint16_t u16x4  __attribute__((ext_vector_type(4)));

#define DEV __device__ __forceinline__

DEV uint32_t pk_bf16(float lo, float hi) {
    uint32_t r;
    asm("v_cvt_pk_bf16_f32 %0, %1, %2" : "=v"(r) : "v"(lo), "v"(hi));
    return r;
}

// ---------------------------------------------------------------------------
// cast 4 weight matrices [1024x1024] fp32 -> bf16
// ---------------------------------------------------------------------------
__global__ __launch_bounds__(256) void cast_w(
    const float* __restrict__ w0, const float* __restrict__ w1,
    const float* __restrict__ w2, const float* __restrict__ w3,
    uint16_t* __restrict__ dst)
{
    const int y = blockIdx.y;
    const float* s = (y == 0) ? w0 : (y == 1) ? w1 : (y == 2) ? w2 : w3;
    uint16_t* d = dst + ((size_t)y << 20);
    const int i = (blockIdx.x * 256 + threadIdx.x) * 8;
    float4 a = *reinterpret_cast<const float4*>(s + i);
    float4 b = *reinterpret_cast<const float4*>(s + i + 4);
    u32x4 w;
    w[0] = pk_bf16(a.x, a.y); w[1] = pk_bf16(a.z, a.w);
    w[2] = pk_bf16(b.x, b.y); w[3] = pk_bf16(b.z, b.w);
    *reinterpret_cast<u32x4*>(d + i) = w;
}

// ---------------------------------------------------------------------------
// QKV projection GEMM: C[4096,1024] = A_f32[4096,1024] @ W_bf16[1024,1024]^T + bias
// blockIdx.z selects (query->Q, key->K, value->V^T)
// 128x128 tile, BK=32, 4 waves x (4x4) mfma_f32_16x16x32_bf16
// ---------------------------------------------------------------------------
#define LDT 40   // padded LDS row stride (elems): 80B -> uniform bank spread

__global__ __launch_bounds__(256) void gemm_qkv(
    const float* __restrict__ inq, const float* __restrict__ ink, const float* __restrict__ inv,
    const uint16_t* __restrict__ wqc, const uint16_t* __restrict__ wkc, const uint16_t* __restrict__ wvc,
    const float* __restrict__ bq, const float* __restrict__ bk, const float* __restrict__ bv,
    uint16_t* __restrict__ Qb, uint16_t* __restrict__ Kb, uint16_t* __restrict__ Vt)
{
    constexpr int Kd = 1024, N = 1024;
    __shared__ uint16_t Al[128 * LDT];
    __shared__ uint16_t Bl[128 * LDT];

    const int z = blockIdx.z;
    const float*    A    = (z == 0) ? inq : (z == 1) ? ink : inv;
    const uint16_t* W    = (z == 0) ? wqc : (z == 1) ? wkc : wvc;
    const float*    bias = (z == 0) ? bq  : (z == 1) ? bk  : bv;

    const int brow = blockIdx.x * 128;
    const int bcol = blockIdx.y * 128;
    const int t    = threadIdx.x;
    const int lane = t & 63;
    const int wid  = t >> 6;
    const int wr   = wid >> 1, wc = wid & 1;

    // staging map: thread -> (row, half-of-32)
    const int srow = t >> 1, shalf = t & 1;
    const float*    asrc = A + (size_t)(brow + srow) * Kd + shalf * 16;
    const uint16_t* bsrc = W + (size_t)(bcol + srow) * Kd + shalf * 16;
    uint16_t* aldst = &Al[srow * LDT + shalf * 16];
    uint16_t* bldst = &Bl[srow * LDT + shalf * 16];

    f32x4 acc[4][4];
#pragma unroll
    for (int i = 0; i < 4; ++i)
#pragma unroll
        for (int j = 0; j < 4; ++j)
#pragma unroll
            for (int e = 0; e < 4; ++e) acc[i][j][e] = 0.f;

    const int frow = lane & 15;          // fragment row/col within 16
    const int koff = (lane >> 4) * 8;    // k offset within 32

    for (int k0 = 0; k0 < Kd; k0 += 32) {
        // --- stage A (fp32 -> bf16) ---
        float4 a0 = *reinterpret_cast<const float4*>(asrc + k0);
        float4 a1 = *reinterpret_cast<const float4*>(asrc + k0 + 4);
        float4 a2 = *reinterpret_cast<const float4*>(asrc + k0 + 8);
        float4 a3 = *reinterpret_cast<const float4*>(asrc + k0 + 12);
        // --- stage B (bf16 passthrough) ---
        u32x4 b0 = *reinterpret_cast<const u32x4*>(bsrc + k0);
        u32x4 b1 = *reinterpret_cast<const u32x4*>(bsrc + k0 + 8);

        u32x4 aw0, aw1;
        aw0[0] = pk_bf16(a0.x, a0.y); aw0[1] = pk_bf16(a0.z, a0.w);
        aw0[2] = pk_bf16(a1.x, a1.y); aw0[3] = pk_bf16(a1.z, a1.w);
        aw1[0] = pk_bf16(a2.x, a2.y); aw1[1] = pk_bf16(a2.z, a2.w);
        aw1[2] = pk_bf16(a3.x, a3.y); aw1[3] = pk_bf16(a3.z, a3.w);

        *reinterpret_cast<u32x4*>(aldst)     = aw0;
        *reinterpret_cast<u32x4*>(aldst + 8) = aw1;
        *reinterpret_cast<u32x4*>(bldst)     = b0;
        *reinterpret_cast<u32x4*>(bldst + 8) = b1;
        __syncthreads();

        bf16x8 af[4], bfrag[4];
#pragma unroll
        for (int fr = 0; fr < 4; ++fr)
            af[fr] = *reinterpret_cast<const bf16x8*>(&Al[(wr * 64 + fr * 16 + frow) * LDT + koff]);
#pragma unroll
        for (int fc = 0; fc < 4; ++fc)
            bfrag[fc] = *reinterpret_cast<const bf16x8*>(&Bl[(wc * 64 + fc * 16 + frow) * LDT + koff]);
#pragma unroll
        for (int fr = 0; fr < 4; ++fr)
#pragma unroll
            for (int fc = 0; fc < 4; ++fc)
                acc[fr][fc] = __builtin_amdgcn_mfma_f32_16x16x32_bf16(af[fr], bfrag[fc], acc[fr][fc], 0, 0, 0);
        __syncthreads();
    }

    // epilogue
    const int m0 = brow + wr * 64;
    const int n0 = bcol + wc * 64;
    if (z < 2) {
        uint16_t* Cb = (z == 0) ? Qb : Kb;
#pragma unroll
        for (int fc = 0; fc < 4; ++fc) {
            const int col = n0 + fc * 16 + frow;
            const float bia = bias[col];
#pragma unroll
            for (int fr = 0; fr < 4; ++fr) {
                const int mrow = m0 + fr * 16 + (lane >> 4) * 4;
                f32x4 a = acc[fr][fc];
                uint32_t w01 = pk_bf16(a[0] + bia, a[1] + bia);
                uint32_t w23 = pk_bf16(a[2] + bia, a[3] + bia);
                Cb[(size_t)(mrow + 0) * N + col] = (uint16_t)(w01 & 0xffff);
                Cb[(size_t)(mrow + 1) * N + col] = (uint16_t)(w01 >> 16);
                Cb[(size_t)(mrow + 2) * N + col] = (uint16_t)(w23 & 0xffff);
                Cb[(size_t)(mrow + 3) * N + col] = (uint16_t)(w23 >> 16);
            }
        }
    } else {
        // V: store transposed per head -> Vt[((b*16+h)*64+d)*2048 + s]
#pragma unroll
        for (int fc = 0; fc < 4; ++fc) {
            const int col = n0 + fc * 16 + frow;
            const int hh = col >> 6, dd = col & 63;
            const float bia = bias[col];
#pragma unroll
            for (int fr = 0; fr < 4; ++fr) {
                const int mrow = m0 + fr * 16 + (lane >> 4) * 4;
                const int bb = mrow >> 11, ss = mrow & 2047;
                f32x4 a = acc[fr][fc];
                uint32_t w01 = pk_bf16(a[0] + bia, a[1] + bia);
                uint32_t w23 = pk_bf16(a[2] + bia, a[3] + bia);
                u16x4 pv;
                pv[0] = (uint16_t)(w01 & 0xffff); pv[1] = (uint16_t)(w01 >> 16);
                pv[2] = (uint16_t)(w23 & 0xffff); pv[3] = (uint16_t)(w23 >> 16);
                *reinterpret_cast<u16x4*>(&Vt[(size_t)((bb * 16 + hh) * 64 + dd) * 2048 + ss]) = pv;
            }
        }
    }
}

// ---------------------------------------------------------------------------
// Flash attention: per (b,h), 4 waves x 32 q-rows, KVBLK=64
// swapped QK^T (mfma(K,Q) -> S^T), in-register online softmax, O^T = Vt @ P^T
// ---------------------------------------------------------------------------
__global__ __launch_bounds__(256) void attn_kernel(
    const uint16_t* __restrict__ Qb, const uint16_t* __restrict__ Kb,
    const uint16_t* __restrict__ Vt, uint16_t* __restrict__ At)
{
    constexpr int S = 2048, E = 1024;
    __shared__ uint16_t Kl[64 * 72];
    __shared__ uint16_t Vl[64 * 72];

    const int bh = blockIdx.y;
    const int b = bh >> 4, h = bh & 15;
    const int t = threadIdx.x;
    const int lane = t & 63, wid = t >> 6;
    const int lo = lane & 31, hi = lane >> 5;
    const int q0 = blockIdx.x * 128 + wid * 32;

    // Q fragments (B-operand): qf[kk] covers d = kk*16 + hi*8 + e, col = q = lo
    bf16x8 qf[4];
    {
        const uint16_t* qrow = Qb + (size_t)(b * S + q0 + lo) * E + h * 64;
#pragma unroll
        for (int kk = 0; kk < 4; ++kk)
            qf[kk] = *reinterpret_cast<const bf16x8*>(qrow + kk * 16 + hi * 8);
    }

    f32x16 oacc[2];
#pragma unroll
    for (int i = 0; i < 16; ++i) { oacc[0][i] = 0.f; oacc[1][i] = 0.f; }
    float mrun = -1e30f, lsum = 0.f;
    const float cexp = 0.18033688011112042f;  // log2(e)/sqrt(Dh) = log2(e)/8

    const uint16_t* Kbase = Kb + (size_t)(b * S) * E + h * 64;
    const uint16_t* Vbase = Vt + (size_t)(bh * 64) * S;

    for (int kv0 = 0; kv0 < S; kv0 += 64) {
        // ---- stage K [64 keys][64 d] and V^T [64 d][64 keys] into LDS ----
        {
            const int r = t >> 2, seg = t & 3;
            const uint16_t* ks = Kbase + (size_t)(kv0 + r) * E + seg * 16;
            u32x4 k0 = *reinterpret_cast<const u32x4*>(ks);
            u32x4 k1 = *reinterpret_cast<const u32x4*>(ks + 8);
            const uint16_t* vs = Vbase + (size_t)r * S + kv0 + seg * 16;
            u32x4 v0 = *reinterpret_cast<const u32x4*>(vs);
            u32x4 v1 = *reinterpret_cast<const u32x4*>(vs + 8);
            *reinterpret_cast<u32x4*>(&Kl[r * 72 + seg * 16])     = k0;
            *reinterpret_cast<u32x4*>(&Kl[r * 72 + seg * 16 + 8]) = k1;
            *reinterpret_cast<u32x4*>(&Vl[r * 72 + seg * 16])     = v0;
            *reinterpret_cast<u32x4*>(&Vl[r * 72 + seg * 16 + 8]) = v1;
        }
        __syncthreads();

        // ---- S^T = K @ Q^T ----
        f32x16 sacc[2];
#pragma unroll
        for (int i = 0; i < 16; ++i) { sacc[0][i] = 0.f; sacc[1][i] = 0.f; }
#pragma unroll
        for (int kk = 0; kk < 4; ++kk) {
            bf16x8 ka0 = *reinterpret_cast<const bf16x8*>(&Kl[lo * 72 + kk * 16 + hi * 8]);
            bf16x8 ka1 = *reinterpret_cast<const bf16x8*>(&Kl[(32 + lo) * 72 + kk * 16 + hi * 8]);
            sacc[0] = __builtin_amdgcn_mfma_f32_32x32x16_bf16(ka0, qf[kk], sacc[0], 0, 0, 0);
            sacc[1] = __builtin_amdgcn_mfma_f32_32x32x16_bf16(ka1, qf[kk], sacc[1], 0, 0, 0);
        }

        // ---- online softmax (q = lo is lane-local; partner lane^32 holds other 32 keys) ----
        float pmax = sacc[0][0];
#pragma unroll
        for (int r = 1; r < 16; ++r) pmax = fmaxf(pmax, sacc[0][r]);
#pragma unroll
        for (int r = 0; r < 16; ++r) pmax = fmaxf(pmax, sacc[1][r]);
        pmax = fmaxf(pmax, __shfl_xor(pmax, 32, 64));

        if (__any(pmax > mrun)) {
            float mnew = fmaxf(mrun, pmax);
            float corr = __builtin_amdgcn_exp2f((mrun - mnew) * cexp);
            lsum *= corr;
#pragma unroll
            for (int i = 0; i < 16; ++i) { oacc[0][i] *= corr; oacc[1][i] *= corr; }
            mrun = mnew;
        }

        // p = exp((s - m)/8), pack pairs to bf16 words
        uint32_t w[16];
        float psum = 0.f;
#pragma unroll
        for (int kf = 0; kf < 2; ++kf)
#pragma unroll
            for (int j = 0; j < 8; ++j) {
                float pa = __builtin_amdgcn_exp2f((sacc[kf][2 * j]     - mrun) * cexp);
                float pb = __builtin_amdgcn_exp2f((sacc[kf][2 * j + 1] - mrun) * cexp);
                psum += pa + pb;
                w[kf * 8 + j] = pk_bf16(pa, pb);
            }
        lsum += psum + __shfl_xor(psum, 32, 64);

        uint32_t x[16];
#pragma unroll
        for (int i = 0; i < 16; ++i) x[i] = __shfl_xor(w[i], 32, 64);

        // ---- PV: O^T[d,q] += Vt[d,key] * P^T[key,q] ----
#pragma unroll
        for (int ks = 0; ks < 4; ++ks) {
            const int base = (ks >> 1) * 8 + (ks & 1) * 4;
            u32x4 pw;
            if (hi == 0) {
                pw[0] = w[base + 0]; pw[1] = w[base + 1];
                pw[2] = x[base + 0]; pw[3] = x[base + 1];
            } else {
                pw[0] = x[base + 2]; pw[1] = x[base + 3];
                pw[2] = w[base + 2]; pw[3] = w[base + 3];
            }
            bf16x8 pf = __builtin_bit_cast(bf16x8, pw);
#pragma unroll
            for (int df = 0; df < 2; ++df) {
                bf16x8 vf = *reinterpret_cast<const bf16x8*>(&Vl[(df * 32 + lo) * 72 + ks * 16 + hi * 8]);
                oacc[df] = __builtin_amdgcn_mfma_f32_32x32x16_bf16(vf, pf, oacc[df], 0, 0, 0);
            }
        }
        __syncthreads();
    }

    // ---- epilogue: normalize + store bf16 to At[b, q, h*64+d] ----
    const float inv = 1.0f / lsum;
    uint16_t* orow = At + (size_t)(b * S + q0 + lo) * E + h * 64;
#pragma unroll
    for (int df = 0; df < 2; ++df)
#pragma unroll
        for (int g = 0; g < 4; ++g) {
            uint32_t w01 = pk_bf16(oacc[df][4 * g + 0] * inv, oacc[df][4 * g + 1] * inv);
            uint32_t w23 = pk_bf16(oacc[df][4 * g + 2] * inv, oacc[df][4 * g + 3] * inv);
            u32x2 o2; o2[0] = w01; o2[1] = w23;
            *reinterpret_cast<u32x2*>(orow + df * 32 + 8 * g + 4 * hi) = o2;
        }
}

// ---------------------------------------------------------------------------
// Output projection: out_f32[4096,1024] = At_bf16 @ Wo^T + bo
// ---------------------------------------------------------------------------
__global__ __launch_bounds__(256) void gemm_out(
    const uint16_t* __restrict__ Atn, const uint16_t* __restrict__ woc,
    const float* __restrict__ bo, float* __restrict__ out)
{
    constexpr int Kd = 1024, N = 1024;
    __shared__ uint16_t Al[128 * LDT];
    __shared__ uint16_t Bl[128 * LDT];

    const int brow = blockIdx.x * 128;
    const int bcol = blockIdx.y * 128;
    const int t    = threadIdx.x;
    const int lane = t & 63;
    const int wid  = t >> 6;
    const int wr   = wid >> 1, wc = wid & 1;

    const int srow = t >> 1, shalf = t & 1;
    const uint16_t* asrc = Atn + (size_t)(brow + srow) * Kd + shalf * 16;
    const uint16_t* bsrc = woc + (size_t)(bcol + srow) * Kd + shalf * 16;
    uint16_t* aldst = &Al[srow * LDT + shalf * 16];
    uint16_t* bldst = &Bl[srow * LDT + shalf * 16];

    f32x4 acc[4][4];
#pragma unroll
    for (int i = 0; i < 4; ++i)
#pragma unroll
        for (int j = 0; j < 4; ++j)
#pragma unroll
            for (int e = 0; e < 4; ++e) acc[i][j][e] = 0.f;

    const int frow = lane & 15;
    const int koff = (lane >> 4) * 8;

    for (int k0 = 0; k0 < Kd; k0 += 32) {
        u32x4 a0 = *reinterpret_cast<const u32x4*>(asrc + k0);
        u32x4 a1 = *reinterpret_cast<const u32x4*>(asrc + k0 + 8);
        u32x4 b0 = *reinterpret_cast<const u32x4*>(bsrc + k0);
        u32x4 b1 = *reinterpret_cast<const u32x4*>(bsrc + k0 + 8);
        *reinterpret_cast<u32x4*>(aldst)     = a0;
        *reinterpret_cast<u32x4*>(aldst + 8) = a1;
        *reinterpret_cast<u32x4*>(bldst)     = b0;
        *reinterpret_cast<u32x4*>(bldst + 8) = b1;
        __syncthreads();

        bf16x8 af[4], bfrag[4];
#pragma unroll
        for (int fr = 0; fr < 4; ++fr)
            af[fr] = *reinterpret_cast<const bf16x8*>(&Al[(wr * 64 + fr * 16 + frow) * LDT + koff]);
#pragma unroll
        for (int fc = 0; fc < 4; ++fc)
            bfrag[fc] = *reinterpret_cast<const bf16x8*>(&Bl[(wc * 64 + fc * 16 + frow) * LDT + koff]);
#pragma unroll
        for (int fr = 0; fr < 4; ++fr)
#pragma unroll
            for (int fc = 0; fc < 4; ++fc)
                acc[fr][fc] = __builtin_amdgcn_mfma_f32_16x16x32_bf16(af[fr], bfrag[fc], acc[fr][fc], 0, 0, 0);
        __syncthreads();
    }

    const int m0 = brow + wr * 64;
    const int n0 = bcol + wc * 64;
#pragma unroll
    for (int fc = 0; fc < 4; ++fc) {
        const int col = n0 + fc * 16 + frow;
        const float bia = bo[col];
#pragma unroll
        for (int fr = 0; fr < 4; ++fr) {
            const int mrow = m0 + fr * 16 + (lane >> 4) * 4;
#pragma unroll
            for (int j = 0; j < 4; ++j)
                out[(size_t)(mrow + j) * N + col] = acc[fr][fc][j] + bia;
        }
    }
}

// ---------------------------------------------------------------------------
extern "C" void kernel_launch(void* const* d_in, const int* in_sizes, int n_in,
                              void* d_out, int out_size, void* d_ws, size_t ws_size,
                              hipStream_t stream)
{
    const float* key   = (const float*)d_in[0];
    const float* query = (const float*)d_in[1];
    const float* value = (const float*)d_in[2];
    const float* Wq = (const float*)d_in[3];
    const float* bq = (const float*)d_in[4];
    const float* Wk = (const float*)d_in[5];
    const float* bk = (const float*)d_in[6];
    const float* Wv = (const float*)d_in[7];
    const float* bv = (const float*)d_in[8];
    const float* Wo = (const float*)d_in[9];
    const float* bo = (const float*)d_in[10];

    uint16_t* ws  = (uint16_t*)d_ws;
    uint16_t* wqc = ws;                       // [1M] bf16
    uint16_t* wkc = ws + (size_t)1  * (1 << 20);
    uint16_t* wvc = ws + (size_t)2  * (1 << 20);
    uint16_t* woc = ws + (size_t)3  * (1 << 20);
    uint16_t* Qb  = ws + (size_t)4  * (1 << 20);  // [4096,1024] bf16
    uint16_t* Kb  = ws + (size_t)8  * (1 << 20);
    uint16_t* Vt  = ws + (size_t)12 * (1 << 20);  // [2,16,64,2048] bf16
    uint16_t* At  = ws + (size_t)16 * (1 << 20);  // [4096,1024] bf16
    float* out = (float*)d_out;

    cast_w<<<dim3(512, 4), 256, 0, stream>>>(Wq, Wk, Wv, Wo, ws);
    gemm_qkv<<<dim3(32, 8, 3), 256, 0, stream>>>(query, key, value,
                                                 wqc, wkc, wvc, bq, bk, bv,
                                                 Qb, Kb, Vt);
    attn_kernel<<<dim3(16, 32), 256, 0, stream>>>(Qb, Kb, Vt, At);
    gemm_out<<<dim3(32, 8), 256, 0, stream>>>(At, woc, bo, out);
}

// Round 3
// 157.822 us; speedup vs baseline: 1.1309x; 1.1309x over previous
//
#include <hip/hip_runtime.h>
#include <hip/hip_bf16.h>
#include <stdint.h>

typedef short    bf16x8 __attribute__((ext_vector_type(8)));
typedef float    f32x4  __attribute__((ext_vector_type(4)));
typedef float    f32x16 __attribute__((ext_vector_type(16)));
typedef uint32_t u32x2  __attribute__((ext_vector_type(2)));
typedef uint32_t u32x4  __attribute__((ext_vector_type(4)));
typedef uint16_t u16x4  __attribute__((ext_vector_type(4)));

#define DEV __device__ __forceinline__
#define AS1 __attribute__((address_space(1)))
#define AS3 __attribute__((address_space(3)))

DEV uint32_t pk_bf16(float lo, float hi) {
    uint32_t r;
    asm("v_cvt_pk_bf16_f32 %0, %1, %2" : "=v"(r) : "v"(lo), "v"(hi));
    return r;
}

// async global->LDS, 16B per lane; LDS dest = wave-uniform base + lane*16
DEV void gload_lds16(const uint16_t* g, uint16_t* l) {
    __builtin_amdgcn_global_load_lds((AS1 const uint32_t*)g, (AS3 uint32_t*)l, 16, 0, 0);
}

// ---------------------------------------------------------------------------
// cast fp32 -> bf16: y in [0,3] -> weights (1M elems), y in [4,6] -> activations (4M)
// ---------------------------------------------------------------------------
__global__ __launch_bounds__(256) void cast_all(
    const float* __restrict__ w0, const float* __restrict__ w1,
    const float* __restrict__ w2, const float* __restrict__ w3,
    const float* __restrict__ aq, const float* __restrict__ ak, const float* __restrict__ av,
    uint16_t* __restrict__ ws)
{
    const int y = blockIdx.y;
    const float* s;
    uint16_t* d;
    if (y < 4) {
        if (blockIdx.x >= 512) return;
        s = (y == 0) ? w0 : (y == 1) ? w1 : (y == 2) ? w2 : w3;
        d = ws + ((size_t)y << 20);
    } else {
        s = (y == 4) ? aq : (y == 5) ? ak : av;
        d = ws + (size_t)(1 << 22) + ((size_t)(y - 4) << 22);
    }
    const size_t i = ((size_t)blockIdx.x * 256 + threadIdx.x) * 8;
    float4 a = *reinterpret_cast<const float4*>(s + i);
    float4 b = *reinterpret_cast<const float4*>(s + i + 4);
    u32x4 w;
    w[0] = pk_bf16(a.x, a.y); w[1] = pk_bf16(a.z, a.w);
    w[2] = pk_bf16(b.x, b.y); w[3] = pk_bf16(b.z, b.w);
    *reinterpret_cast<u32x4*>(d + i) = w;
}

// ---------------------------------------------------------------------------
// m97-structure GEMM: C[4096,1024] = A_bf16[4096,1024] @ W_bf16[1024,1024]^T + bias
// 128x128 tile, BK=32, 4 waves x (4x4) mfma_f32_16x16x32_bf16, global_load_lds staging
// blockIdx.z: 0->Q, 1->K, 2->V (V stored transposed per head)
// ---------------------------------------------------------------------------
__global__ __launch_bounds__(256) void gemm_qkv(
    const uint16_t* __restrict__ Qc, const uint16_t* __restrict__ Kc, const uint16_t* __restrict__ Vc,
    const uint16_t* __restrict__ wqc, const uint16_t* __restrict__ wkc, const uint16_t* __restrict__ wvc,
    const float* __restrict__ bq, const float* __restrict__ bk, const float* __restrict__ bv,
    uint16_t* __restrict__ Qb, uint16_t* __restrict__ Kb, uint16_t* __restrict__ Vt)
{
    constexpr int Kd = 1024, N = 1024;
    __shared__ uint16_t Al[128 * 32];
    __shared__ uint16_t Bl[128 * 32];

    const int z = blockIdx.z;
    const uint16_t* A = (z == 0) ? Qc : (z == 1) ? Kc : Vc;
    const uint16_t* W = (z == 0) ? wqc : (z == 1) ? wkc : wvc;
    const float* bias = (z == 0) ? bq : (z == 1) ? bk : bv;

    const int brow = blockIdx.x * 128;
    const int bcol = blockIdx.y * 128;
    const int t = threadIdx.x, lane = t & 63, wid = t >> 6;
    const int wr = wid >> 1, wc = wid & 1;

    // staging map (chunk c adds 64 rows): row = c*64 + wid*16 + (lane>>2), col = (lane&3)*8
    const int srow = wid * 16 + (lane >> 2);
    const int scol = (lane & 3) * 8;
    const uint16_t* aA = A + (size_t)(brow + srow) * Kd + scol;
    const uint16_t* aW = W + (size_t)(bcol + srow) * Kd + scol;
    uint16_t* lA = &Al[srow * 32 + scol];
    uint16_t* lB = &Bl[srow * 32 + scol];

    f32x4 acc[4][4];
#pragma unroll
    for (int i = 0; i < 4; ++i)
#pragma unroll
        for (int j = 0; j < 4; ++j)
#pragma unroll
            for (int e = 0; e < 4; ++e) acc[i][j][e] = 0.f;

    const int frow = lane & 15;
    const int koff = (lane >> 4) * 8;

    for (int k0 = 0; k0 < Kd; k0 += 32) {
        gload_lds16(aA + k0, lA);
        gload_lds16(aA + k0 + (size_t)64 * Kd, lA + 64 * 32);
        gload_lds16(aW + k0, lB);
        gload_lds16(aW + k0 + (size_t)64 * Kd, lB + 64 * 32);
        __syncthreads();

        bf16x8 af[4], bfr[4];
#pragma unroll
        for (int fr = 0; fr < 4; ++fr)
            af[fr] = *reinterpret_cast<const bf16x8*>(&Al[(wr * 64 + fr * 16 + frow) * 32 + koff]);
#pragma unroll
        for (int fc = 0; fc < 4; ++fc)
            bfr[fc] = *reinterpret_cast<const bf16x8*>(&Bl[(wc * 64 + fc * 16 + frow) * 32 + koff]);
#pragma unroll
        for (int fr = 0; fr < 4; ++fr)
#pragma unroll
            for (int fc = 0; fc < 4; ++fc)
                acc[fr][fc] = __builtin_amdgcn_mfma_f32_16x16x32_bf16(af[fr], bfr[fc], acc[fr][fc], 0, 0, 0);
        __syncthreads();
    }

    const int m0 = brow + wr * 64;
    const int n0 = bcol + wc * 64;
    if (z < 2) {
        uint16_t* Cb = (z == 0) ? Qb : Kb;
#pragma unroll
        for (int fc = 0; fc < 4; ++fc) {
            const int col = n0 + fc * 16 + frow;
            const float bia = bias[col];
#pragma unroll
            for (int fr = 0; fr < 4; ++fr) {
                const int mrow = m0 + fr * 16 + (lane >> 4) * 4;
                f32x4 a = acc[fr][fc];
                uint32_t w01 = pk_bf16(a[0] + bia, a[1] + bia);
                uint32_t w23 = pk_bf16(a[2] + bia, a[3] + bia);
                Cb[(size_t)(mrow + 0) * N + col] = (uint16_t)(w01 & 0xffff);
                Cb[(size_t)(mrow + 1) * N + col] = (uint16_t)(w01 >> 16);
                Cb[(size_t)(mrow + 2) * N + col] = (uint16_t)(w23 & 0xffff);
                Cb[(size_t)(mrow + 3) * N + col] = (uint16_t)(w23 >> 16);
            }
        }
    } else {
        // V: store transposed per head -> Vt[((b*16+h)*64+d)*2048 + s]
#pragma unroll
        for (int fc = 0; fc < 4; ++fc) {
            const int col = n0 + fc * 16 + frow;
            const int hh = col >> 6, dd = col & 63;
            const float bia = bias[col];
#pragma unroll
            for (int fr = 0; fr < 4; ++fr) {
                const int mrow = m0 + fr * 16 + (lane >> 4) * 4;
                const int bb = mrow >> 11, ss = mrow & 2047;
                f32x4 a = acc[fr][fc];
                uint32_t w01 = pk_bf16(a[0] + bia, a[1] + bia);
                uint32_t w23 = pk_bf16(a[2] + bia, a[3] + bia);
                u16x4 pv;
                pv[0] = (uint16_t)(w01 & 0xffff); pv[1] = (uint16_t)(w01 >> 16);
                pv[2] = (uint16_t)(w23 & 0xffff); pv[3] = (uint16_t)(w23 >> 16);
                *reinterpret_cast<u16x4*>(&Vt[(size_t)((bb * 16 + hh) * 64 + dd) * 2048 + ss]) = pv;
            }
        }
    }
}

// ---------------------------------------------------------------------------
// Flash attention: per (b,h), 4 waves x 32 q-rows, KVBLK=64
// swapped QK^T (mfma(K,Q) -> S^T), in-register online softmax, O^T = Vt @ P^T
// ---------------------------------------------------------------------------
__global__ __launch_bounds__(256) void attn_kernel(
    const uint16_t* __restrict__ Qb, const uint16_t* __restrict__ Kb,
    const uint16_t* __restrict__ Vt, uint16_t* __restrict__ At)
{
    constexpr int S = 2048, E = 1024;
    __shared__ uint16_t Kl[64 * 72];
    __shared__ uint16_t Vl[64 * 72];

    const int bh = blockIdx.y;
    const int b = bh >> 4, h = bh & 15;
    const int t = threadIdx.x;
    const int lane = t & 63, wid = t >> 6;
    const int lo = lane & 31, hi = lane >> 5;
    const int q0 = blockIdx.x * 128 + wid * 32;

    bf16x8 qf[4];
    {
        const uint16_t* qrow = Qb + (size_t)(b * S + q0 + lo) * E + h * 64;
#pragma unroll
        for (int kk = 0; kk < 4; ++kk)
            qf[kk] = *reinterpret_cast<const bf16x8*>(qrow + kk * 16 + hi * 8);
    }

    f32x16 oacc[2];
#pragma unroll
    for (int i = 0; i < 16; ++i) { oacc[0][i] = 0.f; oacc[1][i] = 0.f; }
    float mrun = -1e30f, lsum = 0.f;
    const float cexp = 0.18033688011112042f;  // log2(e)/8

    const uint16_t* Kbase = Kb + (size_t)(b * S) * E + h * 64;
    const uint16_t* Vbase = Vt + (size_t)(bh * 64) * S;

    for (int kv0 = 0; kv0 < S; kv0 += 64) {
        {
            const int r = t >> 2, seg = t & 3;
            const uint16_t* ks = Kbase + (size_t)(kv0 + r) * E + seg * 16;
            u32x4 k0 = *reinterpret_cast<const u32x4*>(ks);
            u32x4 k1 = *reinterpret_cast<const u32x4*>(ks + 8);
            const uint16_t* vs = Vbase + (size_t)r * S + kv0 + seg * 16;
            u32x4 v0 = *reinterpret_cast<const u32x4*>(vs);
            u32x4 v1 = *reinterpret_cast<const u32x4*>(vs + 8);
            *reinterpret_cast<u32x4*>(&Kl[r * 72 + seg * 16])     = k0;
            *reinterpret_cast<u32x4*>(&Kl[r * 72 + seg * 16 + 8]) = k1;
            *reinterpret_cast<u32x4*>(&Vl[r * 72 + seg * 16])     = v0;
            *reinterpret_cast<u32x4*>(&Vl[r * 72 + seg * 16 + 8]) = v1;
        }
        __syncthreads();

        f32x16 sacc[2];
#pragma unroll
        for (int i = 0; i < 16; ++i) { sacc[0][i] = 0.f; sacc[1][i] = 0.f; }
#pragma unroll
        for (int kk = 0; kk < 4; ++kk) {
            bf16x8 ka0 = *reinterpret_cast<const bf16x8*>(&Kl[lo * 72 + kk * 16 + hi * 8]);
            bf16x8 ka1 = *reinterpret_cast<const bf16x8*>(&Kl[(32 + lo) * 72 + kk * 16 + hi * 8]);
            sacc[0] = __builtin_amdgcn_mfma_f32_32x32x16_bf16(ka0, qf[kk], sacc[0], 0, 0, 0);
            sacc[1] = __builtin_amdgcn_mfma_f32_32x32x16_bf16(ka1, qf[kk], sacc[1], 0, 0, 0);
        }

        float pmax = sacc[0][0];
#pragma unroll
        for (int r = 1; r < 16; ++r) pmax = fmaxf(pmax, sacc[0][r]);
#pragma unroll
        for (int r = 0; r < 16; ++r) pmax = fmaxf(pmax, sacc[1][r]);
        pmax = fmaxf(pmax, __shfl_xor(pmax, 32, 64));

        if (__any(pmax > mrun)) {
            float mnew = fmaxf(mrun, pmax);
            float corr = __builtin_amdgcn_exp2f((mrun - mnew) * cexp);
            lsum *= corr;
#pragma unroll
            for (int i = 0; i < 16; ++i) { oacc[0][i] *= corr; oacc[1][i] *= corr; }
            mrun = mnew;
        }

        uint32_t w[16];
        float psum = 0.f;
#pragma unroll
        for (int kf = 0; kf < 2; ++kf)
#pragma unroll
            for (int j = 0; j < 8; ++j) {
                float pa = __builtin_amdgcn_exp2f((sacc[kf][2 * j]     - mrun) * cexp);
                float pb = __builtin_amdgcn_exp2f((sacc[kf][2 * j + 1] - mrun) * cexp);
                psum += pa + pb;
                w[kf * 8 + j] = pk_bf16(pa, pb);
            }
        lsum += psum + __shfl_xor(psum, 32, 64);

        uint32_t x[16];
#pragma unroll
        for (int i = 0; i < 16; ++i) x[i] = __shfl_xor(w[i], 32, 64);

#pragma unroll
        for (int ks = 0; ks < 4; ++ks) {
            const int base = (ks >> 1) * 8 + (ks & 1) * 4;
            u32x4 pw;
            if (hi == 0) {
                pw[0] = w[base + 0]; pw[1] = w[base + 1];
                pw[2] = x[base + 0]; pw[3] = x[base + 1];
            } else {
                pw[0] = x[base + 2]; pw[1] = x[base + 3];
                pw[2] = w[base + 2]; pw[3] = w[base + 3];
            }
            bf16x8 pf = __builtin_bit_cast(bf16x8, pw);
#pragma unroll
            for (int df = 0; df < 2; ++df) {
                bf16x8 vf = *reinterpret_cast<const bf16x8*>(&Vl[(df * 32 + lo) * 72 + ks * 16 + hi * 8]);
                oacc[df] = __builtin_amdgcn_mfma_f32_32x32x16_bf16(vf, pf, oacc[df], 0, 0, 0);
            }
        }
        __syncthreads();
    }

    const float inv = 1.0f / lsum;
    uint16_t* orow = At + (size_t)(b * S + q0 + lo) * E + h * 64;
#pragma unroll
    for (int df = 0; df < 2; ++df)
#pragma unroll
        for (int g = 0; g < 4; ++g) {
            uint32_t w01 = pk_bf16(oacc[df][4 * g + 0] * inv, oacc[df][4 * g + 1] * inv);
            uint32_t w23 = pk_bf16(oacc[df][4 * g + 2] * inv, oacc[df][4 * g + 3] * inv);
            u32x2 o2; o2[0] = w01; o2[1] = w23;
            *reinterpret_cast<u32x2*>(orow + df * 32 + 8 * g + 4 * hi) = o2;
        }
}

// ---------------------------------------------------------------------------
// Output projection (m97 structure): out_f32[4096,1024] = At_bf16 @ Wo^T + bo
// ---------------------------------------------------------------------------
__global__ __launch_bounds__(256) void gemm_out(
    const uint16_t* __restrict__ Atn, const uint16_t* __restrict__ woc,
    const float* __restrict__ bo, float* __restrict__ out)
{
    constexpr int Kd = 1024, N = 1024;
    __shared__ uint16_t Al[128 * 32];
    __shared__ uint16_t Bl[128 * 32];

    const int brow = blockIdx.x * 128;
    const int bcol = blockIdx.y * 128;
    const int t = threadIdx.x, lane = t & 63, wid = t >> 6;
    const int wr = wid >> 1, wc = wid & 1;

    const int srow = wid * 16 + (lane >> 2);
    const int scol = (lane & 3) * 8;
    const uint16_t* aA = Atn + (size_t)(brow + srow) * Kd + scol;
    const uint16_t* aW = woc + (size_t)(bcol + srow) * Kd + scol;
    uint16_t* lA = &Al[srow * 32 + scol];
    uint16_t* lB = &Bl[srow * 32 + scol];

    f32x4 acc[4][4];
#pragma unroll
    for (int i = 0; i < 4; ++i)
#pragma unroll
        for (int j = 0; j < 4; ++j)
#pragma unroll
            for (int e = 0; e < 4; ++e) acc[i][j][e] = 0.f;

    const int frow = lane & 15;
    const int koff = (lane >> 4) * 8;

    for (int k0 = 0; k0 < Kd; k0 += 32) {
        gload_lds16(aA + k0, lA);
        gload_lds16(aA + k0 + (size_t)64 * Kd, lA + 64 * 32);
        gload_lds16(aW + k0, lB);
        gload_lds16(aW + k0 + (size_t)64 * Kd, lB + 64 * 32);
        __syncthreads();

        bf16x8 af[4], bfr[4];
#pragma unroll
        for (int fr = 0; fr < 4; ++fr)
            af[fr] = *reinterpret_cast<const bf16x8*>(&Al[(wr * 64 + fr * 16 + frow) * 32 + koff]);
#pragma unroll
        for (int fc = 0; fc < 4; ++fc)
            bfr[fc] = *reinterpret_cast<const bf16x8*>(&Bl[(wc * 64 + fc * 16 + frow) * 32 + koff]);
#pragma unroll
        for (int fr = 0; fr < 4; ++fr)
#pragma unroll
            for (int fc = 0; fc < 4; ++fc)
                acc[fr][fc] = __builtin_amdgcn_mfma_f32_16x16x32_bf16(af[fr], bfr[fc], acc[fr][fc], 0, 0, 0);
        __syncthreads();
    }

    const int m0 = brow + wr * 64;
    const int n0 = bcol + wc * 64;
#pragma unroll
    for (int fc = 0; fc < 4; ++fc) {
        const int col = n0 + fc * 16 + frow;
        const float bia = bo[col];
#pragma unroll
        for (int fr = 0; fr < 4; ++fr) {
            const int mrow = m0 + fr * 16 + (lane >> 4) * 4;
#pragma unroll
            for (int j = 0; j < 4; ++j)
                out[(size_t)(mrow + j) * N + col] = acc[fr][fc][j] + bia;
        }
    }
}

// ---------------------------------------------------------------------------
extern "C" void kernel_launch(void* const* d_in, const int* in_sizes, int n_in,
                              void* d_out, int out_size, void* d_ws, size_t ws_size,
                              hipStream_t stream)
{
    const float* key   = (const float*)d_in[0];
    const float* query = (const float*)d_in[1];
    const float* value = (const float*)d_in[2];
    const float* Wq = (const float*)d_in[3];
    const float* bq = (const float*)d_in[4];
    const float* Wk = (const float*)d_in[5];
    const float* bk = (const float*)d_in[6];
    const float* Wv = (const float*)d_in[7];
    const float* bv = (const float*)d_in[8];
    const float* Wo = (const float*)d_in[9];
    const float* bo = (const float*)d_in[10];

    uint16_t* ws = (uint16_t*)d_ws;
    // layout (elems):
    uint16_t* wqc = ws;                                 // 4 x 1M weights
    uint16_t* wkc = ws + ((size_t)1 << 20);
    uint16_t* wvc = ws + ((size_t)2 << 20);
    uint16_t* woc = ws + ((size_t)3 << 20);
    uint16_t* Qc  = ws + ((size_t)1 << 22);             // 3 x 4M bf16 activations
    uint16_t* Kc  = ws + ((size_t)2 << 22);
    uint16_t* Vc  = ws + ((size_t)3 << 22);
    uint16_t* Qb  = ws + ((size_t)4 << 22);             // projected Q/K, V^T
    uint16_t* Kb  = ws + ((size_t)5 << 22);
    uint16_t* Vt  = ws + ((size_t)6 << 22);
    uint16_t* At  = Qc;                                 // alias: Qc dead after gemm_qkv
    float* out = (float*)d_out;

    cast_all<<<dim3(2048, 7), 256, 0, stream>>>(Wq, Wk, Wv, Wo, query, key, value, ws);
    gemm_qkv<<<dim3(32, 8, 3), 256, 0, stream>>>(Qc, Kc, Vc, wqc, wkc, wvc,
                                                 bq, bk, bv, Qb, Kb, Vt);
    attn_kernel<<<dim3(16, 32), 256, 0, stream>>>(Qb, Kb, Vt, At);
    gemm_out<<<dim3(32, 8), 256, 0, stream>>>(At, woc, bo, out);
}

// Round 5
// 142.897 us; speedup vs baseline: 1.2490x; 1.1044x over previous
//
#include <hip/hip_runtime.h>
#include <hip/hip_bf16.h>
#include <stdint.h>

typedef short    bf16x8 __attribute__((ext_vector_type(8)));
typedef float    f32x4  __attribute__((ext_vector_type(4)));
typedef float    f32x16 __attribute__((ext_vector_type(16)));
typedef uint32_t u32x2  __attribute__((ext_vector_type(2)));
typedef uint32_t u32x4  __attribute__((ext_vector_type(4)));
typedef uint16_t u16x4  __attribute__((ext_vector_type(4)));

#define DEV __device__ __forceinline__
#define AS1 __attribute__((address_space(1)))
#define AS3 __attribute__((address_space(3)))

#define SM_SCALE 0.18033688011112042f   // log2(e)/sqrt(Dh) = log2(e)/8, folded into Wq

DEV uint32_t pk_bf16(float lo, float hi) {
    uint32_t r;
    asm("v_cvt_pk_bf16_f32 %0, %1, %2" : "=v"(r) : "v"(lo), "v"(hi));
    return r;
}

// async global->LDS, 16B per lane; LDS dest = wave-uniform base + lane*16
DEV void gload_lds16(const uint16_t* g, uint16_t* l) {
    __builtin_amdgcn_global_load_lds((AS1 const uint32_t*)g, (AS3 uint32_t*)l, 16, 0, 0);
}

// ---------------------------------------------------------------------------
// cast fp32 -> bf16: y in [0,3] -> weights (1M elems), y in [4,6] -> activations (4M)
// Wq (y==0) is pre-scaled by SM_SCALE so attention scores land in log2 domain.
// ---------------------------------------------------------------------------
__global__ __launch_bounds__(256) void cast_all(
    const float* __restrict__ w0, const float* __restrict__ w1,
    const float* __restrict__ w2, const float* __restrict__ w3,
    const float* __restrict__ aq, const float* __restrict__ ak, const float* __restrict__ av,
    uint16_t* __restrict__ ws)
{
    const int y = blockIdx.y;
    const float* s;
    uint16_t* d;
    if (y < 4) {
        if (blockIdx.x >= 512) return;
        s = (y == 0) ? w0 : (y == 1) ? w1 : (y == 2) ? w2 : w3;
        d = ws + ((size_t)y << 20);
    } else {
        s = (y == 4) ? aq : (y == 5) ? ak : av;
        d = ws + (size_t)(1 << 22) + ((size_t)(y - 4) << 22);
    }
    const float m = (y == 0) ? SM_SCALE : 1.0f;
    const size_t i = ((size_t)blockIdx.x * 256 + threadIdx.x) * 8;
    float4 a = *reinterpret_cast<const float4*>(s + i);
    float4 b = *reinterpret_cast<const float4*>(s + i + 4);
    u32x4 w;
    w[0] = pk_bf16(a.x * m, a.y * m); w[1] = pk_bf16(a.z * m, a.w * m);
    w[2] = pk_bf16(b.x * m, b.y * m); w[3] = pk_bf16(b.z * m, b.w * m);
    *reinterpret_cast<u32x4*>(d + i) = w;
}

// ---------------------------------------------------------------------------
// m97-structure GEMM: C[4096,1024] = A_bf16[4096,1024] @ W_bf16[1024,1024]^T + bias
// 128x128 tile, BK=32, 4 waves x (4x4) mfma_f32_16x16x32_bf16, global_load_lds staging
// blockIdx.z: 0->Q (bias scaled by SM_SCALE), 1->K, 2->V (stored transposed per head)
// ---------------------------------------------------------------------------
__global__ __launch_bounds__(256) void gemm_qkv(
    const uint16_t* __restrict__ Qc, const uint16_t* __restrict__ Kc, const uint16_t* __restrict__ Vc,
    const uint16_t* __restrict__ wqc, const uint16_t* __restrict__ wkc, const uint16_t* __restrict__ wvc,
    const float* __restrict__ bq, const float* __restrict__ bk, const float* __restrict__ bv,
    uint16_t* __restrict__ Qb, uint16_t* __restrict__ Kb, uint16_t* __restrict__ Vt)
{
    constexpr int Kd = 1024, N = 1024;
    __shared__ uint16_t Al[128 * 32];
    __shared__ uint16_t Bl[128 * 32];

    const int z = blockIdx.z;
    const uint16_t* A = (z == 0) ? Qc : (z == 1) ? Kc : Vc;
    const uint16_t* W = (z == 0) ? wqc : (z == 1) ? wkc : wvc;
    const float* bias = (z == 0) ? bq : (z == 1) ? bk : bv;
    const float bs = (z == 0) ? SM_SCALE : 1.0f;

    const int brow = blockIdx.x * 128;
    const int bcol = blockIdx.y * 128;
    const int t = threadIdx.x, lane = t & 63, wid = t >> 6;
    const int wr = wid >> 1, wc = wid & 1;

    const int srow = wid * 16 + (lane >> 2);
    const int scol = (lane & 3) * 8;
    const uint16_t* aA = A + (size_t)(brow + srow) * Kd + scol;
    const uint16_t* aW = W + (size_t)(bcol + srow) * Kd + scol;
    uint16_t* lA = &Al[srow * 32 + scol];
    uint16_t* lB = &Bl[srow * 32 + scol];

    f32x4 acc[4][4];
#pragma unroll
    for (int i = 0; i < 4; ++i)
#pragma unroll
        for (int j = 0; j < 4; ++j)
#pragma unroll
            for (int e = 0; e < 4; ++e) acc[i][j][e] = 0.f;

    const int frow = lane & 15;
    const int koff = (lane >> 4) * 8;

    for (int k0 = 0; k0 < Kd; k0 += 32) {
        gload_lds16(aA + k0, lA);
        gload_lds16(aA + k0 + (size_t)64 * Kd, lA + 64 * 32);
        gload_lds16(aW + k0, lB);
        gload_lds16(aW + k0 + (size_t)64 * Kd, lB + 64 * 32);
        __syncthreads();

        bf16x8 af[4], bfr[4];
#pragma unroll
        for (int fr = 0; fr < 4; ++fr)
            af[fr] = *reinterpret_cast<const bf16x8*>(&Al[(wr * 64 + fr * 16 + frow) * 32 + koff]);
#pragma unroll
        for (int fc = 0; fc < 4; ++fc)
            bfr[fc] = *reinterpret_cast<const bf16x8*>(&Bl[(wc * 64 + fc * 16 + frow) * 32 + koff]);
#pragma unroll
        for (int fr = 0; fr < 4; ++fr)
#pragma unroll
            for (int fc = 0; fc < 4; ++fc)
                acc[fr][fc] = __builtin_amdgcn_mfma_f32_16x16x32_bf16(af[fr], bfr[fc], acc[fr][fc], 0, 0, 0);
        __syncthreads();
    }

    const int m0 = brow + wr * 64;
    const int n0 = bcol + wc * 64;
    if (z < 2) {
        uint16_t* Cb = (z == 0) ? Qb : Kb;
#pragma unroll
        for (int fc = 0; fc < 4; ++fc) {
            const int col = n0 + fc * 16 + frow;
            const float bia = bias[col] * bs;
#pragma unroll
            for (int fr = 0; fr < 4; ++fr) {
                const int mrow = m0 + fr * 16 + (lane >> 4) * 4;
                f32x4 a = acc[fr][fc];
                uint32_t w01 = pk_bf16(a[0] + bia, a[1] + bia);
                uint32_t w23 = pk_bf16(a[2] + bia, a[3] + bia);
                Cb[(size_t)(mrow + 0) * N + col] = (uint16_t)(w01 & 0xffff);
                Cb[(size_t)(mrow + 1) * N + col] = (uint16_t)(w01 >> 16);
                Cb[(size_t)(mrow + 2) * N + col] = (uint16_t)(w23 & 0xffff);
                Cb[(size_t)(mrow + 3) * N + col] = (uint16_t)(w23 >> 16);
            }
        }
    } else {
        // V: store transposed per head -> Vt[((b*16+h)*64+d)*2048 + s]
#pragma unroll
        for (int fc = 0; fc < 4; ++fc) {
            const int col = n0 + fc * 16 + frow;
            const int hh = col >> 6, dd = col & 63;
            const float bia = bias[col];
#pragma unroll
            for (int fr = 0; fr < 4; ++fr) {
                const int mrow = m0 + fr * 16 + (lane >> 4) * 4;
                const int bb = mrow >> 11, ss = mrow & 2047;
                f32x4 a = acc[fr][fc];
                uint32_t w01 = pk_bf16(a[0] + bia, a[1] + bia);
                uint32_t w23 = pk_bf16(a[2] + bia, a[3] + bia);
                u16x4 pv;
                pv[0] = (uint16_t)(w01 & 0xffff); pv[1] = (uint16_t)(w01 >> 16);
                pv[2] = (uint16_t)(w23 & 0xffff); pv[3] = (uint16_t)(w23 >> 16);
                *reinterpret_cast<u16x4*>(&Vt[(size_t)((bb * 16 + hh) * 64 + dd) * 2048 + ss]) = pv;
            }
        }
    }
}

// ---------------------------------------------------------------------------
// Flash attention: per (b,h), 4 waves x 32 q-rows, KVBLK=64
// swapped QK^T (mfma(K,Q) -> S^T), in-register online softmax (scores pre-scaled
// to log2 domain), O^T = Vt @ P^T.
// Round-5: keep dbuf/defer-max/tree-max/setprio from round-4; P-exchange
// REVERTED to round-3-verified __shfl_xor (permlane direction unproven).
// ---------------------------------------------------------------------------
__global__ __launch_bounds__(256) void attn_kernel(
    const uint16_t* __restrict__ Qb, const uint16_t* __restrict__ Kb,
    const uint16_t* __restrict__ Vt, uint16_t* __restrict__ At)
{
    constexpr int S = 2048, E = 1024;
    __shared__ uint16_t Kl[2][64 * 72];
    __shared__ uint16_t Vl[2][64 * 72];

    const int bh = blockIdx.y;
    const int b = bh >> 4, h = bh & 15;
    const int t = threadIdx.x;
    const int lane = t & 63, wid = t >> 6;
    const int lo = lane & 31, hi = lane >> 5;
    const int q0 = blockIdx.x * 128 + wid * 32;

    bf16x8 qf[4];
    {
        const uint16_t* qrow = Qb + (size_t)(b * S + q0 + lo) * E + h * 64;
#pragma unroll
        for (int kk = 0; kk < 4; ++kk)
            qf[kk] = *reinterpret_cast<const bf16x8*>(qrow + kk * 16 + hi * 8);
    }

    f32x16 oacc[2];
#pragma unroll
    for (int i = 0; i < 16; ++i) { oacc[0][i] = 0.f; oacc[1][i] = 0.f; }
    float mrun = -1e30f, lsum = 0.f;

    const uint16_t* Kbase = Kb + (size_t)(b * S) * E + h * 64;
    const uint16_t* Vbase = Vt + (size_t)(bh * 64) * S;

    const int r = t >> 2, seg = t & 3;   // staging map: row r, 16-elem segment seg

    // ---- prologue: stage tile 0 ----
    {
        const uint16_t* ks = Kbase + (size_t)r * E + seg * 16;
        const uint16_t* vs = Vbase + (size_t)r * S + seg * 16;
        u32x4 k0 = *reinterpret_cast<const u32x4*>(ks);
        u32x4 k1 = *reinterpret_cast<const u32x4*>(ks + 8);
        u32x4 v0 = *reinterpret_cast<const u32x4*>(vs);
        u32x4 v1 = *reinterpret_cast<const u32x4*>(vs + 8);
        *reinterpret_cast<u32x4*>(&Kl[0][r * 72 + seg * 16])     = k0;
        *reinterpret_cast<u32x4*>(&Kl[0][r * 72 + seg * 16 + 8]) = k1;
        *reinterpret_cast<u32x4*>(&Vl[0][r * 72 + seg * 16])     = v0;
        *reinterpret_cast<u32x4*>(&Vl[0][r * 72 + seg * 16 + 8]) = v1;
        __syncthreads();
    }

    auto tile = [&](const uint16_t* Klb, const uint16_t* Vlb,
                    uint16_t* Kn, uint16_t* Vn, int kv0) {
        const bool more = (kv0 + 64) < S;
        // ---- issue next-tile loads early (latency hides under compute) ----
        u32x4 nk0, nk1, nv0, nv1;
        if (more) {
            const uint16_t* ks = Kbase + (size_t)(kv0 + 64 + r) * E + seg * 16;
            const uint16_t* vs = Vbase + (size_t)r * S + (kv0 + 64) + seg * 16;
            nk0 = *reinterpret_cast<const u32x4*>(ks);
            nk1 = *reinterpret_cast<const u32x4*>(ks + 8);
            nv0 = *reinterpret_cast<const u32x4*>(vs);
            nv1 = *reinterpret_cast<const u32x4*>(vs + 8);
        }

        // ---- S^T = K @ Q^T (scores already in log2 domain) ----
        f32x16 sacc[2];
#pragma unroll
        for (int i = 0; i < 16; ++i) { sacc[0][i] = 0.f; sacc[1][i] = 0.f; }
        __builtin_amdgcn_s_setprio(1);
#pragma unroll
        for (int kk = 0; kk < 4; ++kk) {
            bf16x8 ka0 = *reinterpret_cast<const bf16x8*>(&Klb[lo * 72 + kk * 16 + hi * 8]);
            bf16x8 ka1 = *reinterpret_cast<const bf16x8*>(&Klb[(32 + lo) * 72 + kk * 16 + hi * 8]);
            sacc[0] = __builtin_amdgcn_mfma_f32_32x32x16_bf16(ka0, qf[kk], sacc[0], 0, 0, 0);
            sacc[1] = __builtin_amdgcn_mfma_f32_32x32x16_bf16(ka1, qf[kk], sacc[1], 0, 0, 0);
        }
        __builtin_amdgcn_s_setprio(0);

        // ---- tree max over 32 values + partner half ----
        float tm[16];
#pragma unroll
        for (int i = 0; i < 16; ++i) tm[i] = fmaxf(sacc[0][i], sacc[1][i]);
#pragma unroll
        for (int s = 8; s > 0; s >>= 1)
#pragma unroll
            for (int i = 0; i < 8; ++i)
                if (i < s) tm[i] = fmaxf(tm[i], tm[i + s]);
        float pmax = tm[0];
        pmax = fmaxf(pmax, __shfl_xor(pmax, 32, 64));

        // ---- defer-max: rescale only when max grew by > 3 (P <= 2^3 = 8) ----
        if (!__all(pmax - mrun <= 3.0f)) {
            float mnew = fmaxf(mrun, pmax);
            float corr = __builtin_amdgcn_exp2f(mrun - mnew);
            lsum *= corr;
#pragma unroll
            for (int i = 0; i < 16; ++i) { oacc[0][i] *= corr; oacc[1][i] *= corr; }
            mrun = mnew;
        }

        // ---- P = exp2(S - m), packed to bf16 pairs; 4-way partial sums ----
        uint32_t w[16];
        float ps0 = 0.f, ps1 = 0.f, ps2 = 0.f, ps3 = 0.f;
#pragma unroll
        for (int kf = 0; kf < 2; ++kf)
#pragma unroll
            for (int j = 0; j < 8; ++j) {
                float pa = __builtin_amdgcn_exp2f(sacc[kf][2 * j]     - mrun);
                float pb = __builtin_amdgcn_exp2f(sacc[kf][2 * j + 1] - mrun);
                if (j & 1) { ps0 += pa; ps1 += pb; } else { ps2 += pa; ps3 += pb; }
                w[kf * 8 + j] = pk_bf16(pa, pb);
            }
        float psum = (ps0 + ps1) + (ps2 + ps3);
        lsum += psum + __shfl_xor(psum, 32, 64);

        // ---- P exchange across lane^32 (round-3 verified shfl_xor path) ----
        uint32_t x[16];
#pragma unroll
        for (int i = 0; i < 16; ++i) x[i] = __shfl_xor(w[i], 32, 64);

        // ---- PV: O^T[d,q] += Vt[d,key] * P^T[key,q] ----
        __builtin_amdgcn_s_setprio(1);
#pragma unroll
        for (int ks = 0; ks < 4; ++ks) {
            const int base = (ks >> 1) * 8 + (ks & 1) * 4;
            u32x4 pw;
            if (hi == 0) {
                pw[0] = w[base + 0]; pw[1] = w[base + 1];
                pw[2] = x[base + 0]; pw[3] = x[base + 1];
            } else {
                pw[0] = x[base + 2]; pw[1] = x[base + 3];
                pw[2] = w[base + 2]; pw[3] = w[base + 3];
            }
            bf16x8 pf = __builtin_bit_cast(bf16x8, pw);
#pragma unroll
            for (int df = 0; df < 2; ++df) {
                bf16x8 vf = *reinterpret_cast<const bf16x8*>(&Vlb[(df * 32 + lo) * 72 + ks * 16 + hi * 8]);
                oacc[df] = __builtin_amdgcn_mfma_f32_32x32x16_bf16(vf, pf, oacc[df], 0, 0, 0);
            }
        }
        __builtin_amdgcn_s_setprio(0);

        // ---- write next tile into alternate buffer; single barrier ----
        if (more) {
            *reinterpret_cast<u32x4*>(&Kn[r * 72 + seg * 16])     = nk0;
            *reinterpret_cast<u32x4*>(&Kn[r * 72 + seg * 16 + 8]) = nk1;
            *reinterpret_cast<u32x4*>(&Vn[r * 72 + seg * 16])     = nv0;
            *reinterpret_cast<u32x4*>(&Vn[r * 72 + seg * 16 + 8]) = nv1;
        }
        __syncthreads();
    };

    for (int kv0 = 0; kv0 < S; kv0 += 128) {
        tile(Kl[0], Vl[0], Kl[1], Vl[1], kv0);
        tile(Kl[1], Vl[1], Kl[0], Vl[0], kv0 + 64);
    }

    const float inv = 1.0f / lsum;
    uint16_t* orow = At + (size_t)(b * S + q0 + lo) * E + h * 64;
#pragma unroll
    for (int df = 0; df < 2; ++df)
#pragma unroll
        for (int g = 0; g < 4; ++g) {
            uint32_t w01 = pk_bf16(oacc[df][4 * g + 0] * inv, oacc[df][4 * g + 1] * inv);
            uint32_t w23 = pk_bf16(oacc[df][4 * g + 2] * inv, oacc[df][4 * g + 3] * inv);
            u32x2 o2; o2[0] = w01; o2[1] = w23;
            *reinterpret_cast<u32x2*>(orow + df * 32 + 8 * g + 4 * hi) = o2;
        }
}

// ---------------------------------------------------------------------------
// Output projection (m97 structure): out_f32[4096,1024] = At_bf16 @ Wo^T + bo
// ---------------------------------------------------------------------------
__global__ __launch_bounds__(256) void gemm_out(
    const uint16_t* __restrict__ Atn, const uint16_t* __restrict__ woc,
    const float* __restrict__ bo, float* __restrict__ out)
{
    constexpr int Kd = 1024, N = 1024;
    __shared__ uint16_t Al[128 * 32];
    __shared__ uint16_t Bl[128 * 32];

    const int brow = blockIdx.x * 128;
    const int bcol = blockIdx.y * 128;
    const int t = threadIdx.x, lane = t & 63, wid = t >> 6;
    const int wr = wid >> 1, wc = wid & 1;

    const int srow = wid * 16 + (lane >> 2);
    const int scol = (lane & 3) * 8;
    const uint16_t* aA = Atn + (size_t)(brow + srow) * Kd + scol;
    const uint16_t* aW = woc + (size_t)(bcol + srow) * Kd + scol;
    uint16_t* lA = &Al[srow * 32 + scol];
    uint16_t* lB = &Bl[srow * 32 + scol];

    f32x4 acc[4][4];
#pragma unroll
    for (int i = 0; i < 4; ++i)
#pragma unroll
        for (int j = 0; j < 4; ++j)
#pragma unroll
            for (int e = 0; e < 4; ++e) acc[i][j][e] = 0.f;

    const int frow = lane & 15;
    const int koff = (lane >> 4) * 8;

    for (int k0 = 0; k0 < Kd; k0 += 32) {
        gload_lds16(aA + k0, lA);
        gload_lds16(aA + k0 + (size_t)64 * Kd, lA + 64 * 32);
        gload_lds16(aW + k0, lB);
        gload_lds16(aW + k0 + (size_t)64 * Kd, lB + 64 * 32);
        __syncthreads();

        bf16x8 af[4], bfr[4];
#pragma unroll
        for (int fr = 0; fr < 4; ++fr)
            af[fr] = *reinterpret_cast<const bf16x8*>(&Al[(wr * 64 + fr * 16 + frow) * 32 + koff]);
#pragma unroll
        for (int fc = 0; fc < 4; ++fc)
            bfr[fc] = *reinterpret_cast<const bf16x8*>(&Bl[(wc * 64 + fc * 16 + frow) * 32 + koff]);
#pragma unroll
        for (int fr = 0; fr < 4; ++fr)
#pragma unroll
            for (int fc = 0; fc < 4; ++fc)
                acc[fr][fc] = __builtin_amdgcn_mfma_f32_16x16x32_bf16(af[fr], bfr[fc], acc[fr][fc], 0, 0, 0);
        __syncthreads();
    }

    const int m0 = brow + wr * 64;
    const int n0 = bcol + wc * 64;
#pragma unroll
    for (int fc = 0; fc < 4; ++fc) {
        const int col = n0 + fc * 16 + frow;
        const float bia = bo[col];
#pragma unroll
        for (int fr = 0; fr < 4; ++fr) {
            const int mrow = m0 + fr * 16 + (lane >> 4) * 4;
#pragma unroll
            for (int j = 0; j < 4; ++j)
                out[(size_t)(mrow + j) * N + col] = acc[fr][fc][j] + bia;
        }
    }
}

// ---------------------------------------------------------------------------
extern "C" void kernel_launch(void* const* d_in, const int* in_sizes, int n_in,
                              void* d_out, int out_size, void* d_ws, size_t ws_size,
                              hipStream_t stream)
{
    const float* key   = (const float*)d_in[0];
    const float* query = (const float*)d_in[1];
    const float* value = (const float*)d_in[2];
    const float* Wq = (const float*)d_in[3];
    const float* bq = (const float*)d_in[4];
    const float* Wk = (const float*)d_in[5];
    const float* bk = (const float*)d_in[6];
    const float* Wv = (const float*)d_in[7];
    const float* bv = (const float*)d_in[8];
    const float* Wo = (const float*)d_in[9];
    const float* bo = (const float*)d_in[10];

    uint16_t* ws = (uint16_t*)d_ws;
    uint16_t* wqc = ws;                                 // 4 x 1M weights
    uint16_t* wkc = ws + ((size_t)1 << 20);
    uint16_t* wvc = ws + ((size_t)2 << 20);
    uint16_t* woc = ws + ((size_t)3 << 20);
    uint16_t* Qc  = ws + ((size_t)1 << 22);             // 3 x 4M bf16 activations
    uint16_t* Kc  = ws + ((size_t)2 << 22);
    uint16_t* Vc  = ws + ((size_t)3 << 22);
    uint16_t* Qb  = ws + ((size_t)4 << 22);             // projected Q/K, V^T
    uint16_t* Kb  = ws + ((size_t)5 << 22);
    uint16_t* Vt  = ws + ((size_t)6 << 22);
    uint16_t* At  = Qc;                                 // alias: Qc dead after gemm_qkv
    float* out = (float*)d_out;

    cast_all<<<dim3(2048, 7), 256, 0, stream>>>(Wq, Wk, Wv, Wo, query, key, value, ws);
    gemm_qkv<<<dim3(32, 8, 3), 256, 0, stream>>>(Qc, Kc, Vc, wqc, wkc, wvc,
                                                 bq, bk, bv, Qb, Kb, Vt);
    attn_kernel<<<dim3(16, 32), 256, 0, stream>>>(Qb, Kb, Vt, At);
    gemm_out<<<dim3(32, 8), 256, 0, stream>>>(At, woc, bo, out);
}

// Round 6
// 138.497 us; speedup vs baseline: 1.2887x; 1.0318x over previous
//
#include <hip/hip_runtime.h>
#include <hip/hip_bf16.h>
#include <stdint.h>

typedef short    bf16x8 __attribute__((ext_vector_type(8)));
typedef float    f32x4  __attribute__((ext_vector_type(4)));
typedef float    f32x16 __attribute__((ext_vector_type(16)));
typedef uint32_t u32x2  __attribute__((ext_vector_type(2)));
typedef uint32_t u32x4  __attribute__((ext_vector_type(4)));
typedef uint16_t u16x4  __attribute__((ext_vector_type(4)));

#define DEV __device__ __forceinline__
#define AS1 __attribute__((address_space(1)))
#define AS3 __attribute__((address_space(3)))

#define SM_SCALE 0.18033688011112042f   // log2(e)/sqrt(Dh) = log2(e)/8, folded into Wq

DEV uint32_t pk_bf16(float lo, float hi) {
    uint32_t r;
    asm("v_cvt_pk_bf16_f32 %0, %1, %2" : "=v"(r) : "v"(lo), "v"(hi));
    return r;
}

// async global->LDS, 16B per lane; LDS dest = wave-uniform base + lane*16
DEV void gload_lds16(const uint16_t* g, uint16_t* l) {
    __builtin_amdgcn_global_load_lds((AS1 const uint32_t*)g, (AS3 uint32_t*)l, 16, 0, 0);
}

// v_permlane32_swap_b32 a, b: a.hi(rows 2-3) <-> b.lo(rows 0-1).
// After: a[l] = l<32 ? a_old[l] : b_old[l-32];  b[l] = l<32 ? a_old[l+32] : b_old[l].
// Direction evidence: round-4 (swapped operands) failed, round-5 (shfl ref) passed.
DEV void plane32_swap(uint32_t& a, uint32_t& b) {
    asm("v_permlane32_swap_b32 %0, %1" : "+v"(a), "+v"(b));
}

// ---------------------------------------------------------------------------
// cast fp32 -> bf16: y in [0,3] -> weights (1M elems), y in [4,6] -> activations (4M)
// Wq (y==0) is pre-scaled by SM_SCALE so attention scores land in log2 domain.
// ---------------------------------------------------------------------------
__global__ __launch_bounds__(256) void cast_all(
    const float* __restrict__ w0, const float* __restrict__ w1,
    const float* __restrict__ w2, const float* __restrict__ w3,
    const float* __restrict__ aq, const float* __restrict__ ak, const float* __restrict__ av,
    uint16_t* __restrict__ ws)
{
    const int y = blockIdx.y;
    const float* s;
    uint16_t* d;
    if (y < 4) {
        if (blockIdx.x >= 512) return;
        s = (y == 0) ? w0 : (y == 1) ? w1 : (y == 2) ? w2 : w3;
        d = ws + ((size_t)y << 20);
    } else {
        s = (y == 4) ? aq : (y == 5) ? ak : av;
        d = ws + (size_t)(1 << 22) + ((size_t)(y - 4) << 22);
    }
    const float m = (y == 0) ? SM_SCALE : 1.0f;
    const size_t i = ((size_t)blockIdx.x * 256 + threadIdx.x) * 8;
    float4 a = *reinterpret_cast<const float4*>(s + i);
    float4 b = *reinterpret_cast<const float4*>(s + i + 4);
    u32x4 w;
    w[0] = pk_bf16(a.x * m, a.y * m); w[1] = pk_bf16(a.z * m, a.w * m);
    w[2] = pk_bf16(b.x * m, b.y * m); w[3] = pk_bf16(b.z * m, b.w * m);
    *reinterpret_cast<u32x4*>(d + i) = w;
}

// ---------------------------------------------------------------------------
// m97-structure GEMM: C[4096,1024] = A_bf16[4096,1024] @ W_bf16[1024,1024]^T + bias
// 128x128 tile, BK=32, 4 waves x (4x4) mfma_f32_16x16x32_bf16, global_load_lds staging
// blockIdx.z: 0->Q (bias scaled by SM_SCALE), 1->K, 2->V (stored transposed per head)
// ---------------------------------------------------------------------------
__global__ __launch_bounds__(256) void gemm_qkv(
    const uint16_t* __restrict__ Qc, const uint16_t* __restrict__ Kc, const uint16_t* __restrict__ Vc,
    const uint16_t* __restrict__ wqc, const uint16_t* __restrict__ wkc, const uint16_t* __restrict__ wvc,
    const float* __restrict__ bq, const float* __restrict__ bk, const float* __restrict__ bv,
    uint16_t* __restrict__ Qb, uint16_t* __restrict__ Kb, uint16_t* __restrict__ Vt)
{
    constexpr int Kd = 1024, N = 1024;
    __shared__ uint16_t Al[128 * 32];
    __shared__ uint16_t Bl[128 * 32];

    const int z = blockIdx.z;
    const uint16_t* A = (z == 0) ? Qc : (z == 1) ? Kc : Vc;
    const uint16_t* W = (z == 0) ? wqc : (z == 1) ? wkc : wvc;
    const float* bias = (z == 0) ? bq : (z == 1) ? bk : bv;
    const float bs = (z == 0) ? SM_SCALE : 1.0f;

    const int brow = blockIdx.x * 128;
    const int bcol = blockIdx.y * 128;
    const int t = threadIdx.x, lane = t & 63, wid = t >> 6;
    const int wr = wid >> 1, wc = wid & 1;

    const int srow = wid * 16 + (lane >> 2);
    const int scol = (lane & 3) * 8;
    const uint16_t* aA = A + (size_t)(brow + srow) * Kd + scol;
    const uint16_t* aW = W + (size_t)(bcol + srow) * Kd + scol;
    uint16_t* lA = &Al[srow * 32 + scol];
    uint16_t* lB = &Bl[srow * 32 + scol];

    f32x4 acc[4][4];
#pragma unroll
    for (int i = 0; i < 4; ++i)
#pragma unroll
        for (int j = 0; j < 4; ++j)
#pragma unroll
            for (int e = 0; e < 4; ++e) acc[i][j][e] = 0.f;

    const int frow = lane & 15;
    const int koff = (lane >> 4) * 8;

    for (int k0 = 0; k0 < Kd; k0 += 32) {
        gload_lds16(aA + k0, lA);
        gload_lds16(aA + k0 + (size_t)64 * Kd, lA + 64 * 32);
        gload_lds16(aW + k0, lB);
        gload_lds16(aW + k0 + (size_t)64 * Kd, lB + 64 * 32);
        __syncthreads();

        bf16x8 af[4], bfr[4];
#pragma unroll
        for (int fr = 0; fr < 4; ++fr)
            af[fr] = *reinterpret_cast<const bf16x8*>(&Al[(wr * 64 + fr * 16 + frow) * 32 + koff]);
#pragma unroll
        for (int fc = 0; fc < 4; ++fc)
            bfr[fc] = *reinterpret_cast<const bf16x8*>(&Bl[(wc * 64 + fc * 16 + frow) * 32 + koff]);
#pragma unroll
        for (int fr = 0; fr < 4; ++fr)
#pragma unroll
            for (int fc = 0; fc < 4; ++fc)
                acc[fr][fc] = __builtin_amdgcn_mfma_f32_16x16x32_bf16(af[fr], bfr[fc], acc[fr][fc], 0, 0, 0);
        __syncthreads();
    }

    const int m0 = brow + wr * 64;
    const int n0 = bcol + wc * 64;
    if (z < 2) {
        uint16_t* Cb = (z == 0) ? Qb : Kb;
#pragma unroll
        for (int fc = 0; fc < 4; ++fc) {
            const int col = n0 + fc * 16 + frow;
            const float bia = bias[col] * bs;
#pragma unroll
            for (int fr = 0; fr < 4; ++fr) {
                const int mrow = m0 + fr * 16 + (lane >> 4) * 4;
                f32x4 a = acc[fr][fc];
                uint32_t w01 = pk_bf16(a[0] + bia, a[1] + bia);
                uint32_t w23 = pk_bf16(a[2] + bia, a[3] + bia);
                Cb[(size_t)(mrow + 0) * N + col] = (uint16_t)(w01 & 0xffff);
                Cb[(size_t)(mrow + 1) * N + col] = (uint16_t)(w01 >> 16);
                Cb[(size_t)(mrow + 2) * N + col] = (uint16_t)(w23 & 0xffff);
                Cb[(size_t)(mrow + 3) * N + col] = (uint16_t)(w23 >> 16);
            }
        }
    } else {
        // V: store transposed per head -> Vt[((b*16+h)*64+d)*2048 + s]
#pragma unroll
        for (int fc = 0; fc < 4; ++fc) {
            const int col = n0 + fc * 16 + frow;
            const int hh = col >> 6, dd = col & 63;
            const float bia = bias[col];
#pragma unroll
            for (int fr = 0; fr < 4; ++fr) {
                const int mrow = m0 + fr * 16 + (lane >> 4) * 4;
                const int bb = mrow >> 11, ss = mrow & 2047;
                f32x4 a = acc[fr][fc];
                uint32_t w01 = pk_bf16(a[0] + bia, a[1] + bia);
                uint32_t w23 = pk_bf16(a[2] + bia, a[3] + bia);
                u16x4 pv;
                pv[0] = (uint16_t)(w01 & 0xffff); pv[1] = (uint16_t)(w01 >> 16);
                pv[2] = (uint16_t)(w23 & 0xffff); pv[3] = (uint16_t)(w23 >> 16);
                *reinterpret_cast<u16x4*>(&Vt[(size_t)((bb * 16 + hh) * 64 + dd) * 2048 + ss]) = pv;
            }
        }
    }
}

// ---------------------------------------------------------------------------
// Flash attention: per (b,h), 4 waves x 32 q-rows, KVBLK=64
// swapped QK^T (mfma(K,Q) -> S^T), in-register online softmax (scores pre-scaled
// to log2 domain), O^T = Vt @ P^T.
// Round-6: P-exchange via permlane32_swap (corrected operand order); lsum
// cross-half exchange deferred to epilogue (corr is uniform across lane^32).
// ---------------------------------------------------------------------------
__global__ __launch_bounds__(256) void attn_kernel(
    const uint16_t* __restrict__ Qb, const uint16_t* __restrict__ Kb,
    const uint16_t* __restrict__ Vt, uint16_t* __restrict__ At)
{
    constexpr int S = 2048, E = 1024;
    __shared__ uint16_t Kl[2][64 * 72];
    __shared__ uint16_t Vl[2][64 * 72];

    const int bh = blockIdx.y;
    const int b = bh >> 4, h = bh & 15;
    const int t = threadIdx.x;
    const int lane = t & 63, wid = t >> 6;
    const int lo = lane & 31, hi = lane >> 5;
    const int q0 = blockIdx.x * 128 + wid * 32;

    bf16x8 qf[4];
    {
        const uint16_t* qrow = Qb + (size_t)(b * S + q0 + lo) * E + h * 64;
#pragma unroll
        for (int kk = 0; kk < 4; ++kk)
            qf[kk] = *reinterpret_cast<const bf16x8*>(qrow + kk * 16 + hi * 8);
    }

    f32x16 oacc[2];
#pragma unroll
    for (int i = 0; i < 16; ++i) { oacc[0][i] = 0.f; oacc[1][i] = 0.f; }
    float mrun = -1e30f, lsum = 0.f;

    const uint16_t* Kbase = Kb + (size_t)(b * S) * E + h * 64;
    const uint16_t* Vbase = Vt + (size_t)(bh * 64) * S;

    const int r = t >> 2, seg = t & 3;   // staging map: row r, 16-elem segment seg

    // ---- prologue: stage tile 0 ----
    {
        const uint16_t* ks = Kbase + (size_t)r * E + seg * 16;
        const uint16_t* vs = Vbase + (size_t)r * S + seg * 16;
        u32x4 k0 = *reinterpret_cast<const u32x4*>(ks);
        u32x4 k1 = *reinterpret_cast<const u32x4*>(ks + 8);
        u32x4 v0 = *reinterpret_cast<const u32x4*>(vs);
        u32x4 v1 = *reinterpret_cast<const u32x4*>(vs + 8);
        *reinterpret_cast<u32x4*>(&Kl[0][r * 72 + seg * 16])     = k0;
        *reinterpret_cast<u32x4*>(&Kl[0][r * 72 + seg * 16 + 8]) = k1;
        *reinterpret_cast<u32x4*>(&Vl[0][r * 72 + seg * 16])     = v0;
        *reinterpret_cast<u32x4*>(&Vl[0][r * 72 + seg * 16 + 8]) = v1;
        __syncthreads();
    }

    auto tile = [&](const uint16_t* Klb, const uint16_t* Vlb,
                    uint16_t* Kn, uint16_t* Vn, int kv0) {
        const bool more = (kv0 + 64) < S;
        // ---- issue next-tile loads early (latency hides under compute) ----
        u32x4 nk0, nk1, nv0, nv1;
        if (more) {
            const uint16_t* ks = Kbase + (size_t)(kv0 + 64 + r) * E + seg * 16;
            const uint16_t* vs = Vbase + (size_t)r * S + (kv0 + 64) + seg * 16;
            nk0 = *reinterpret_cast<const u32x4*>(ks);
            nk1 = *reinterpret_cast<const u32x4*>(ks + 8);
            nv0 = *reinterpret_cast<const u32x4*>(vs);
            nv1 = *reinterpret_cast<const u32x4*>(vs + 8);
        }

        // ---- S^T = K @ Q^T (scores already in log2 domain) ----
        f32x16 sacc[2];
#pragma unroll
        for (int i = 0; i < 16; ++i) { sacc[0][i] = 0.f; sacc[1][i] = 0.f; }
        __builtin_amdgcn_s_setprio(1);
#pragma unroll
        for (int kk = 0; kk < 4; ++kk) {
            bf16x8 ka0 = *reinterpret_cast<const bf16x8*>(&Klb[lo * 72 + kk * 16 + hi * 8]);
            bf16x8 ka1 = *reinterpret_cast<const bf16x8*>(&Klb[(32 + lo) * 72 + kk * 16 + hi * 8]);
            sacc[0] = __builtin_amdgcn_mfma_f32_32x32x16_bf16(ka0, qf[kk], sacc[0], 0, 0, 0);
            sacc[1] = __builtin_amdgcn_mfma_f32_32x32x16_bf16(ka1, qf[kk], sacc[1], 0, 0, 0);
        }
        __builtin_amdgcn_s_setprio(0);

        // ---- tree max over 32 values + partner half ----
        float tm[16];
#pragma unroll
        for (int i = 0; i < 16; ++i) tm[i] = fmaxf(sacc[0][i], sacc[1][i]);
#pragma unroll
        for (int s = 8; s > 0; s >>= 1)
#pragma unroll
            for (int i = 0; i < 8; ++i)
                if (i < s) tm[i] = fmaxf(tm[i], tm[i + s]);
        float pmax = tm[0];
        pmax = fmaxf(pmax, __shfl_xor(pmax, 32, 64));

        // ---- defer-max: rescale only when max grew by > 3 (P <= 2^3 = 8) ----
        if (!__all(pmax - mrun <= 3.0f)) {
            float mnew = fmaxf(mrun, pmax);
            float corr = __builtin_amdgcn_exp2f(mrun - mnew);
            lsum *= corr;
#pragma unroll
            for (int i = 0; i < 16; ++i) { oacc[0][i] *= corr; oacc[1][i] *= corr; }
            mrun = mnew;
        }

        // ---- P = exp2(S - m), packed to bf16 pairs; 4-way partial sums ----
        uint32_t w[16];
        float ps0 = 0.f, ps1 = 0.f, ps2 = 0.f, ps3 = 0.f;
#pragma unroll
        for (int kf = 0; kf < 2; ++kf)
#pragma unroll
            for (int j = 0; j < 8; ++j) {
                float pa = __builtin_amdgcn_exp2f(sacc[kf][2 * j]     - mrun);
                float pb = __builtin_amdgcn_exp2f(sacc[kf][2 * j + 1] - mrun);
                if (j & 1) { ps0 += pa; ps1 += pb; } else { ps2 += pa; ps3 += pb; }
                w[kf * 8 + j] = pk_bf16(pa, pb);
            }
        lsum += (ps0 + ps1) + (ps2 + ps3);   // cross-half exchange deferred to epilogue

        // ---- PV: O^T[d,q] += Vt[d,key] * P^T[key,q] ----
        // P exchange via permlane32_swap: swap(w0,w2) -> {pw0, pw2}; swap(w1,w3) -> {pw1, pw3}
        __builtin_amdgcn_s_setprio(1);
#pragma unroll
        for (int ks = 0; ks < 4; ++ks) {
            const int base = (ks >> 1) * 8 + (ks & 1) * 4;
            uint32_t p0 = w[base + 0], p2 = w[base + 2];
            uint32_t p1 = w[base + 1], p3 = w[base + 3];
            plane32_swap(p0, p2);
            plane32_swap(p1, p3);
            u32x4 pw; pw[0] = p0; pw[1] = p1; pw[2] = p2; pw[3] = p3;
            bf16x8 pf = __builtin_bit_cast(bf16x8, pw);
#pragma unroll
            for (int df = 0; df < 2; ++df) {
                bf16x8 vf = *reinterpret_cast<const bf16x8*>(&Vlb[(df * 32 + lo) * 72 + ks * 16 + hi * 8]);
                oacc[df] = __builtin_amdgcn_mfma_f32_32x32x16_bf16(vf, pf, oacc[df], 0, 0, 0);
            }
        }
        __builtin_amdgcn_s_setprio(0);

        // ---- write next tile into alternate buffer; single barrier ----
        if (more) {
            *reinterpret_cast<u32x4*>(&Kn[r * 72 + seg * 16])     = nk0;
            *reinterpret_cast<u32x4*>(&Kn[r * 72 + seg * 16 + 8]) = nk1;
            *reinterpret_cast<u32x4*>(&Vn[r * 72 + seg * 16])     = nv0;
            *reinterpret_cast<u32x4*>(&Vn[r * 72 + seg * 16 + 8]) = nv1;
        }
        __syncthreads();
    };

    for (int kv0 = 0; kv0 < S; kv0 += 128) {
        tile(Kl[0], Vl[0], Kl[1], Vl[1], kv0);
        tile(Kl[1], Vl[1], Kl[0], Vl[0], kv0 + 64);
    }

    // deferred cross-half l exchange (corr was uniform across lane^32 all along)
    lsum += __shfl_xor(lsum, 32, 64);
    const float inv = 1.0f / lsum;
    uint16_t* orow = At + (size_t)(b * S + q0 + lo) * E + h * 64;
#pragma unroll
    for (int df = 0; df < 2; ++df)
#pragma unroll
        for (int g = 0; g < 4; ++g) {
            uint32_t w01 = pk_bf16(oacc[df][4 * g + 0] * inv, oacc[df][4 * g + 1] * inv);
            uint32_t w23 = pk_bf16(oacc[df][4 * g + 2] * inv, oacc[df][4 * g + 3] * inv);
            u32x2 o2; o2[0] = w01; o2[1] = w23;
            *reinterpret_cast<u32x2*>(orow + df * 32 + 8 * g + 4 * hi) = o2;
        }
}

// ---------------------------------------------------------------------------
// Output projection (m97 structure): out_f32[4096,1024] = At_bf16 @ Wo^T + bo
// ---------------------------------------------------------------------------
__global__ __launch_bounds__(256) void gemm_out(
    const uint16_t* __restrict__ Atn, const uint16_t* __restrict__ woc,
    const float* __restrict__ bo, float* __restrict__ out)
{
    constexpr int Kd = 1024, N = 1024;
    __shared__ uint16_t Al[128 * 32];
    __shared__ uint16_t Bl[128 * 32];

    const int brow = blockIdx.x * 128;
    const int bcol = blockIdx.y * 128;
    const int t = threadIdx.x, lane = t & 63, wid = t >> 6;
    const int wr = wid >> 1, wc = wid & 1;

    const int srow = wid * 16 + (lane >> 2);
    const int scol = (lane & 3) * 8;
    const uint16_t* aA = Atn + (size_t)(brow + srow) * Kd + scol;
    const uint16_t* aW = woc + (size_t)(bcol + srow) * Kd + scol;
    uint16_t* lA = &Al[srow * 32 + scol];
    uint16_t* lB = &Bl[srow * 32 + scol];

    f32x4 acc[4][4];
#pragma unroll
    for (int i = 0; i < 4; ++i)
#pragma unroll
        for (int j = 0; j < 4; ++j)
#pragma unroll
            for (int e = 0; e < 4; ++e) acc[i][j][e] = 0.f;

    const int frow = lane & 15;
    const int koff = (lane >> 4) * 8;

    for (int k0 = 0; k0 < Kd; k0 += 32) {
        gload_lds16(aA + k0, lA);
        gload_lds16(aA + k0 + (size_t)64 * Kd, lA + 64 * 32);
        gload_lds16(aW + k0, lB);
        gload_lds16(aW + k0 + (size_t)64 * Kd, lB + 64 * 32);
        __syncthreads();

        bf16x8 af[4], bfr[4];
#pragma unroll
        for (int fr = 0; fr < 4; ++fr)
            af[fr] = *reinterpret_cast<const bf16x8*>(&Al[(wr * 64 + fr * 16 + frow) * 32 + koff]);
#pragma unroll
        for (int fc = 0; fc < 4; ++fc)
            bfr[fc] = *reinterpret_cast<const bf16x8*>(&Bl[(wc * 64 + fc * 16 + frow) * 32 + koff]);
#pragma unroll
        for (int fr = 0; fr < 4; ++fr)
#pragma unroll
            for (int fc = 0; fc < 4; ++fc)
                acc[fr][fc] = __builtin_amdgcn_mfma_f32_16x16x32_bf16(af[fr], bfr[fc], acc[fr][fc], 0, 0, 0);
        __syncthreads();
    }

    const int m0 = brow + wr * 64;
    const int n0 = bcol + wc * 64;
#pragma unroll
    for (int fc = 0; fc < 4; ++fc) {
        const int col = n0 + fc * 16 + frow;
        const float bia = bo[col];
#pragma unroll
        for (int fr = 0; fr < 4; ++fr) {
            const int mrow = m0 + fr * 16 + (lane >> 4) * 4;
#pragma unroll
            for (int j = 0; j < 4; ++j)
                out[(size_t)(mrow + j) * N + col] = acc[fr][fc][j] + bia;
        }
    }
}

// ---------------------------------------------------------------------------
extern "C" void kernel_launch(void* const* d_in, const int* in_sizes, int n_in,
                              void* d_out, int out_size, void* d_ws, size_t ws_size,
                              hipStream_t stream)
{
    const float* key   = (const float*)d_in[0];
    const float* query = (const float*)d_in[1];
    const float* value = (const float*)d_in[2];
    const float* Wq = (const float*)d_in[3];
    const float* bq = (const float*)d_in[4];
    const float* Wk = (const float*)d_in[5];
    const float* bk = (const float*)d_in[6];
    const float* Wv = (const float*)d_in[7];
    const float* bv = (const float*)d_in[8];
    const float* Wo = (const float*)d_in[9];
    const float* bo = (const float*)d_in[10];

    uint16_t* ws = (uint16_t*)d_ws;
    uint16_t* wqc = ws;                                 // 4 x 1M weights
    uint16_t* wkc = ws + ((size_t)1 << 20);
    uint16_t* wvc = ws + ((size_t)2 << 20);
    uint16_t* woc = ws + ((size_t)3 << 20);
    uint16_t* Qc  = ws + ((size_t)1 << 22);             // 3 x 4M bf16 activations
    uint16_t* Kc  = ws + ((size_t)2 << 22);
    uint16_t* Vc  = ws + ((size_t)3 << 22);
    uint16_t* Qb  = ws + ((size_t)4 << 22);             // projected Q/K, V^T
    uint16_t* Kb  = ws + ((size_t)5 << 22);
    uint16_t* Vt  = ws + ((size_t)6 << 22);
    uint16_t* At  = Qc;                                 // alias: Qc dead after gemm_qkv
    float* out = (float*)d_out;

    cast_all<<<dim3(2048, 7), 256, 0, stream>>>(Wq, Wk, Wv, Wo, query, key, value, ws);
    gemm_qkv<<<dim3(32, 8, 3), 256, 0, stream>>>(Qc, Kc, Vc, wqc, wkc, wvc,
                                                 bq, bk, bv, Qb, Kb, Vt);
    attn_kernel<<<dim3(16, 32), 256, 0, stream>>>(Qb, Kb, Vt, At);
    gemm_out<<<dim3(32, 8), 256, 0, stream>>>(At, woc, bo, out);
}